// Round 1
// baseline (426.797 us; speedup 1.0000x reference)
//
#include <hip/hip_runtime.h>

#define DIM 224
#define NVOX 32768
#define NBATCH 2

typedef __attribute__((ext_vector_type(8))) short bf16x8;
typedef __attribute__((ext_vector_type(4))) float f32x4;

__device__ __forceinline__ unsigned short f2bf(float f){
  unsigned int u = __builtin_bit_cast(unsigned int, f);
  u += 0x7fffu + ((u >> 16) & 1u);          // RNE
  return (unsigned short)(u >> 16);
}
__device__ __forceinline__ float bf2f(unsigned short s){
  unsigned int u = ((unsigned int)s) << 16;
  return __builtin_bit_cast(float, u);
}
__device__ __forceinline__ float gelu_f(float x){
  return 0.5f * x * (1.0f + erff(x * 0.70710678118654752440f));
}

// ---------------------------------------------------------------------------
// Shared GEMM core: out[64 v][224 o] += A[64 v][224 c] * W[o][c]^T
// Atile: [64][256] bf16, row-swizzled: logical unit u (8 ch) stored at
//        up = u ^ (v&31). Wtile: [224][40] bf16 (padded rows, staged per K-step).
// 4 waves: wm = v-half (32 rows), wn = o-half (112 cols, 7 frags).
// mfma_f32_16x16x32_bf16: A lane(row=l&15, k=(l>>4)*8+j), B lane(col=l&15, same k),
// D lane(col=l&15, row=(l>>4)*4+r).
// ---------------------------------------------------------------------------
__device__ __forceinline__ void gemm_core(const unsigned short* Atile,
                                          unsigned short* Wtile,
                                          const unsigned short* __restrict__ wmat,
                                          int tid, int lane, int wm, int wn,
                                          f32x4 acc[2][7])
{
  for (int ks = 0; ks < 7; ++ks){
    if (ks) __syncthreads();                 // protect Wtile from prev reads
    #pragma unroll
    for (int it = 0; it < 4; ++it){
      int idx = tid + it * 256;
      if (idx < 896){
        int o = idx >> 2, kp = idx & 3;
        *(bf16x8*)&Wtile[o * 40 + kp * 8] =
            *(const bf16x8*)&wmat[o * 224 + ks * 32 + kp * 8];
      }
    }
    __syncthreads();
    bf16x8 af[2];
    #pragma unroll
    for (int m = 0; m < 2; ++m){
      int row = wm * 32 + m * 16 + (lane & 15);
      int up  = ((ks << 2) | (lane >> 4)) ^ (row & 31);
      af[m] = *(const bf16x8*)&Atile[row * 256 + up * 8];
    }
    #pragma unroll
    for (int n = 0; n < 7; ++n){
      int o = wn * 112 + n * 16 + (lane & 15);
      bf16x8 wf = *(const bf16x8*)&Wtile[o * 40 + (lane >> 4) * 8];
      acc[0][n] = __builtin_amdgcn_mfma_f32_16x16x32_bf16(af[0], wf, acc[0][n], 0, 0, 0);
      acc[1][n] = __builtin_amdgcn_mfma_f32_16x16x32_bf16(af[1], wf, acc[1][n], 0, 0, 0);
    }
  }
}

// ---------------------------------------------------------------------------
// KW: convert the 5 weight matrices to bf16; zero stats accumulators
// ---------------------------------------------------------------------------
__global__ void k_wconv(const float* __restrict__ w1, const float* __restrict__ w2,
                        const float* __restrict__ w3, const float* __restrict__ w4,
                        const float* __restrict__ w5,
                        unsigned short* __restrict__ dst, float* __restrict__ stats)
{
  int i = blockIdx.x * 256 + threadIdx.x;
  if (blockIdx.x == 0 && threadIdx.x < 16) stats[threadIdx.x] = 0.f;
  if (i < 5 * DIM * DIM){
    int m = i / (DIM * DIM), r = i - m * (DIM * DIM);
    const float* s = (m == 0) ? w1 : (m == 1) ? w2 : (m == 2) ? w3 : (m == 3) ? w4 : w5;
    dst[i] = f2bf(s[r]);
  }
}

// ---------------------------------------------------------------------------
// K1: h0[b][v][c] = conv1(x) + b1  (bf16), + global sum/sumsq atomics
// ---------------------------------------------------------------------------
__global__ __launch_bounds__(256, 2) void k_gemm1(
    const float* __restrict__ x, const unsigned short* __restrict__ w1,
    const float* __restrict__ b1, unsigned short* __restrict__ h0,
    float* __restrict__ stats)
{
  __shared__ __align__(16) unsigned short Atile[64 * 256];
  __shared__ __align__(16) unsigned short Wtile[224 * 40];
  __shared__ float red[8];
  int tid = threadIdx.x;
  int lane = tid & 63, wid = tid >> 6;
  int wm = wid & 1, wn = wid >> 1;
  int blk = blockIdx.x;
  int b = blk >> 9;
  int vb = (blk & 511) << 6;

  { // stage: transpose x[c][v-tile] -> Atile[v][c] bf16 (swizzled units)
    int v = tid & 63;
    const float* xb = x + (size_t)b * DIM * NVOX + vb + v;
    int sw = v & 31;
    for (int j0 = tid >> 6; j0 < 28; j0 += 4){
      bf16x8 pv;
      #pragma unroll
      for (int i = 0; i < 8; ++i)
        pv[i] = (short)f2bf(xb[(size_t)(j0 * 8 + i) * NVOX]);
      *(bf16x8*)&Atile[v * 256 + (j0 ^ sw) * 8] = pv;
    }
  }
  __syncthreads();

  f32x4 zz = {0.f, 0.f, 0.f, 0.f};
  f32x4 acc[2][7];
  #pragma unroll
  for (int m = 0; m < 2; ++m)
    #pragma unroll
    for (int n = 0; n < 7; ++n) acc[m][n] = zz;

  gemm_core(Atile, Wtile, w1, tid, lane, wm, wn, acc);
  __syncthreads();                            // Atile reads done; reuse as Ebf

  unsigned short* Ebf = Atile;
  float lsum = 0.f, lsq = 0.f;
  #pragma unroll
  for (int n = 0; n < 7; ++n){
    int col = wn * 112 + n * 16 + (lane & 15);
    float bias = b1[col];
    #pragma unroll
    for (int m = 0; m < 2; ++m){
      #pragma unroll
      for (int r = 0; r < 4; ++r){
        float val = acc[m][n][r] + bias;
        lsum += val; lsq += val * val;
        int vl = wm * 32 + m * 16 + (lane >> 4) * 4 + r;
        Ebf[vl * 224 + col] = f2bf(val);
      }
    }
  }
  #pragma unroll
  for (int off = 32; off; off >>= 1){
    lsum += __shfl_down(lsum, off);
    lsq  += __shfl_down(lsq,  off);
  }
  if (lane == 0){ red[wid * 2] = lsum; red[wid * 2 + 1] = lsq; }
  __syncthreads();
  if (tid == 0){
    atomicAdd(&stats[0 + b], red[0] + red[2] + red[4] + red[6]);
    atomicAdd(&stats[2 + b], red[1] + red[3] + red[5] + red[7]);
  }
  for (int idx = tid; idx < 64 * 28; idx += 256){
    int vl = idx / 28, u = idx - vl * 28;
    *(bf16x8*)&h0[((size_t)b * NVOX + vb + vl) * DIM + u * 8] =
        *(const bf16x8*)&Ebf[vl * 224 + u * 8];
  }
}

// ---------------------------------------------------------------------------
// KS: finalize GroupNorm stats -> per-channel affine A=rstd*g, B=beta-mu*A
// ---------------------------------------------------------------------------
__global__ void k_stats(const float* __restrict__ stats, int soff,
                        const float* __restrict__ g, const float* __restrict__ be,
                        float* __restrict__ Aout, float* __restrict__ Bout)
{
  int tid = threadIdx.x;
  const float invN = 1.0f / (float)((size_t)DIM * NVOX);
  for (int i = tid; i < 2 * DIM; i += 256){
    int b = i / DIM, c = i - b * DIM;
    float mu   = stats[soff + b] * invN;
    float var  = stats[soff + 2 + b] * invN - mu * mu;
    float rstd = rsqrtf(var + 1e-5f);
    float a = rstd * g[c];
    Aout[i] = a;
    Bout[i] = be[c] - mu * a;
  }
}

// ---------------------------------------------------------------------------
// K3: in-place h = gelu(h0 * A1 + B1)
// ---------------------------------------------------------------------------
__global__ void k_act(unsigned short* __restrict__ h,
                      const float* __restrict__ A1, const float* __restrict__ B1)
{
  const size_t total = (size_t)NBATCH * NVOX * 28;
  for (size_t idx = (size_t)blockIdx.x * 256 + threadIdx.x; idx < total;
       idx += (size_t)2048 * 256){
    int u = (int)(idx % 28);
    size_t bv = idx / 28;                 // b*NVOX + v
    int b = (int)(bv >> 15);
    unsigned short* p = h + bv * DIM + u * 8;
    bf16x8 hv = *(const bf16x8*)p;
    const float* Ap = A1 + b * DIM + u * 8;
    const float* Bp = B1 + b * DIM + u * 8;
    #pragma unroll
    for (int i = 0; i < 8; ++i){
      float f = bf2f((unsigned short)hv[i]) * Ap[i] + Bp[i];
      hv[i] = (short)f2bf(gelu_f(f));
    }
    *(bf16x8*)p = hv;
  }
}

// ---------------------------------------------------------------------------
// K4: s = gelu(conv21(t1)) + gelu(conv22(t2)) + gelu(conv23(t3)), + stats2
// t1 = h[d-s_g, h, w]; t2 = h[d-3, h-s_g-3, w-3]; t3 = h[d-6, h-6, w-s_g-6]
// ---------------------------------------------------------------------------
__global__ __launch_bounds__(256, 2) void k_shift(
    const unsigned short* __restrict__ h, const unsigned short* __restrict__ wall,
    const float* __restrict__ b21, const float* __restrict__ b22,
    const float* __restrict__ b23,
    unsigned short* __restrict__ sout, float* __restrict__ stats)
{
  __shared__ __align__(16) unsigned short Atile[64 * 256];
  __shared__ __align__(16) unsigned short Wtile[224 * 40];
  __shared__ float red[8];
  int tid = threadIdx.x;
  int lane = tid & 63, wid = tid >> 6;
  int wm = wid & 1, wn = wid >> 1;
  int blk = blockIdx.x;
  int b = blk >> 9;
  int vb = (blk & 511) << 6;

  f32x4 zz = {0.f, 0.f, 0.f, 0.f};
  f32x4 sacc[2][7];
  #pragma unroll
  for (int m = 0; m < 2; ++m)
    #pragma unroll
    for (int n = 0; n < 7; ++n) sacc[m][n] = zz;

  for (int cv = 0; cv < 3; ++cv){
    __syncthreads();                        // protect Atile/Wtile from prev reads
    #pragma unroll
    for (int it = 0; it < 8; ++it){
      int slot = tid + it * 256;            // 2048 slots = [64 v][32 units]
      int v = slot >> 5, up = slot & 31;
      int u = up ^ (v & 31);
      bf16x8 val = {0, 0, 0, 0, 0, 0, 0, 0};
      if (u < 28){
        int g = u >> 2;
        int vg = vb + v;
        int d = vg >> 10, hh = (vg >> 5) & 31, w = vg & 31;
        int dd, hy, wx;
        if (cv == 0){ dd = d - (g - 3); hy = hh;           wx = w; }
        else if (cv == 1){ dd = d - 3;  hy = hh - (g - 3) - 3; wx = w - 3; }
        else { dd = d - 6;              hy = hh - 6;       wx = w - (g - 3) - 6; }
        if ((unsigned)dd < 32u && (unsigned)hy < 32u && (unsigned)wx < 32u){
          size_t vsrc = ((size_t)dd << 10) + (hy << 5) + wx;
          val = *(const bf16x8*)&h[((size_t)b * NVOX + vsrc) * DIM + u * 8];
        }
      }
      *(bf16x8*)&Atile[slot * 8] = val;
    }
    __syncthreads();

    f32x4 acc[2][7];
    #pragma unroll
    for (int m = 0; m < 2; ++m)
      #pragma unroll
      for (int n = 0; n < 7; ++n) acc[m][n] = zz;

    const unsigned short* wmat = wall + (size_t)(cv + 1) * DIM * DIM;
    gemm_core(Atile, Wtile, wmat, tid, lane, wm, wn, acc);

    const float* bp = (cv == 0) ? b21 : (cv == 1) ? b22 : b23;
    #pragma unroll
    for (int n = 0; n < 7; ++n){
      float bias = bp[wn * 112 + n * 16 + (lane & 15)];
      #pragma unroll
      for (int m = 0; m < 2; ++m)
        #pragma unroll
        for (int r = 0; r < 4; ++r)
          sacc[m][n][r] += gelu_f(acc[m][n][r] + bias);
    }
  }
  __syncthreads();                          // last Atile reads done

  unsigned short* Ebf = Atile;
  float lsum = 0.f, lsq = 0.f;
  #pragma unroll
  for (int n = 0; n < 7; ++n){
    int col = wn * 112 + n * 16 + (lane & 15);
    #pragma unroll
    for (int m = 0; m < 2; ++m){
      #pragma unroll
      for (int r = 0; r < 4; ++r){
        float val = sacc[m][n][r];
        lsum += val; lsq += val * val;
        int vl = wm * 32 + m * 16 + (lane >> 4) * 4 + r;
        Ebf[vl * 224 + col] = f2bf(val);
      }
    }
  }
  #pragma unroll
  for (int off = 32; off; off >>= 1){
    lsum += __shfl_down(lsum, off);
    lsq  += __shfl_down(lsq,  off);
  }
  if (lane == 0){ red[wid * 2] = lsum; red[wid * 2 + 1] = lsq; }
  __syncthreads();
  if (tid == 0){
    atomicAdd(&stats[4 + b], red[0] + red[2] + red[4] + red[6]);
    atomicAdd(&stats[6 + b], red[1] + red[3] + red[5] + red[7]);
  }
  for (int idx = tid; idx < 64 * 28; idx += 256){
    int vl = idx / 28, u = idx - vl * 28;
    *(bf16x8*)&sout[((size_t)b * NVOX + vb + vl) * DIM + u * 8] =
        *(const bf16x8*)&Ebf[vl * 224 + u * 8];
  }
}

// ---------------------------------------------------------------------------
// K6: y = conv3(gn2(s)) + b3 + x_orig   (output in [b][c][v] via LDS transpose)
// ---------------------------------------------------------------------------
__global__ __launch_bounds__(256, 2) void k_out(
    const unsigned short* __restrict__ sbf, const unsigned short* __restrict__ w3,
    const float* __restrict__ b3,
    const float* __restrict__ A2, const float* __restrict__ B2,
    const float* __restrict__ xorig, float* __restrict__ y)
{
  __shared__ __align__(16) unsigned short Atile[64 * 256];
  __shared__ __align__(16) unsigned short Wtile[224 * 40];
  int tid = threadIdx.x;
  int lane = tid & 63, wid = tid >> 6;
  int wm = wid & 1, wn = wid >> 1;
  int blk = blockIdx.x;
  int b = blk >> 9;
  int vb = (blk & 511) << 6;

  #pragma unroll
  for (int it = 0; it < 8; ++it){
    int slot = tid + it * 256;
    int v = slot >> 5, up = slot & 31;
    int u = up ^ (v & 31);
    bf16x8 val = {0, 0, 0, 0, 0, 0, 0, 0};
    if (u < 28){
      bf16x8 sv = *(const bf16x8*)&sbf[((size_t)b * NVOX + vb + v) * DIM + u * 8];
      const float* Ap = A2 + b * DIM + u * 8;
      const float* Bp = B2 + b * DIM + u * 8;
      #pragma unroll
      for (int i = 0; i < 8; ++i)
        val[i] = (short)f2bf(bf2f((unsigned short)sv[i]) * Ap[i] + Bp[i]);
    }
    *(bf16x8*)&Atile[slot * 8] = val;
  }
  __syncthreads();

  f32x4 zz = {0.f, 0.f, 0.f, 0.f};
  f32x4 acc[2][7];
  #pragma unroll
  for (int m = 0; m < 2; ++m)
    #pragma unroll
    for (int n = 0; n < 7; ++n) acc[m][n] = zz;

  gemm_core(Atile, Wtile, w3, tid, lane, wm, wn, acc);

  float bias[7];
  #pragma unroll
  for (int n = 0; n < 7; ++n) bias[n] = b3[wn * 112 + n * 16 + (lane & 15)];

  float* Et = (float*)Atile;               // [112][65] f32 transpose buffer
  for (int half = 0; half < 2; ++half){
    __syncthreads();
    if (wn == half){
      #pragma unroll
      for (int m = 0; m < 2; ++m)
        #pragma unroll
        for (int n = 0; n < 7; ++n)
          #pragma unroll
          for (int r = 0; r < 4; ++r){
            int ol = n * 16 + (lane & 15);
            int vl = wm * 32 + m * 16 + (lane >> 4) * 4 + r;
            Et[ol * 65 + vl] = acc[m][n][r] + bias[n];
          }
    }
    __syncthreads();
    int v = tid & 63;
    for (int row = tid >> 6; row < 112; row += 4){
      int o = half * 112 + row;
      size_t gi = ((size_t)b * DIM + o) * NVOX + vb + v;
      y[gi] = Et[row * 65 + v] + xorig[gi];
    }
  }
}

// ---------------------------------------------------------------------------
extern "C" void kernel_launch(void* const* d_in, const int* in_sizes, int n_in,
                              void* d_out, int out_size, void* d_ws, size_t ws_size,
                              hipStream_t stream)
{
  const float* x    = (const float*)d_in[0];
  const float* w1f  = (const float*)d_in[1];
  const float* b1   = (const float*)d_in[2];
  const float* w21f = (const float*)d_in[3];
  const float* b21  = (const float*)d_in[4];
  const float* w22f = (const float*)d_in[5];
  const float* b22  = (const float*)d_in[6];
  const float* w23f = (const float*)d_in[7];
  const float* b23  = (const float*)d_in[8];
  const float* w3f  = (const float*)d_in[9];
  const float* b3   = (const float*)d_in[10];
  const float* n1g  = (const float*)d_in[11];
  const float* n1b  = (const float*)d_in[12];
  const float* n2g  = (const float*)d_in[13];
  const float* n2b  = (const float*)d_in[14];
  float* y = (float*)d_out;

  float* stats = (float*)d_ws;                                  // 16 floats
  float* A1 = stats + 16; float* B1 = A1 + 448;
  float* A2 = B1 + 448;   float* B2 = A2 + 448;
  unsigned short* Wbf = (unsigned short*)((char*)d_ws + 8192);  // 5*224*224 bf16
  unsigned short* sbf = (unsigned short*)((char*)d_ws + 524288);// 2*32768*224 bf16
  unsigned short* hbf = (unsigned short*)d_out;                 // h0/h (dead before K6 writes y)

  k_wconv<<<980, 256, 0, stream>>>(w1f, w21f, w22f, w23f, w3f, Wbf, stats);
  k_gemm1<<<1024, 256, 0, stream>>>(x, Wbf, b1, hbf, stats);
  k_stats<<<1, 256, 0, stream>>>(stats, 0, n1g, n1b, A1, B1);
  k_act<<<2048, 256, 0, stream>>>(hbf, A1, B1);
  k_shift<<<1024, 256, 0, stream>>>(hbf, Wbf, b21, b22, b23, sbf, stats);
  k_stats<<<1, 256, 0, stream>>>(stats, 4, n2g, n2b, A2, B2);
  k_out<<<1024, 256, 0, stream>>>(sbf, Wbf + 4 * DIM * DIM, b3, A2, B2, x, y);
}

// Round 6
// 347.796 us; speedup vs baseline: 1.2271x; 1.2271x over previous
//
#include <hip/hip_runtime.h>

#define DIM 224
#define NVOX 32768

typedef __attribute__((ext_vector_type(8))) short bf16x8;
typedef __attribute__((ext_vector_type(4))) float f32x4;
typedef unsigned short ushort_t;

__device__ __forceinline__ unsigned short f2bf(float f){
  unsigned int u = __builtin_bit_cast(unsigned int, f);
  u += 0x7fffu + ((u >> 16) & 1u);          // RNE
  return (unsigned short)(u >> 16);
}
__device__ __forceinline__ float bf2f(unsigned short s){
  unsigned int u = ((unsigned int)s) << 16;
  return __builtin_bit_cast(float, u);
}
__device__ __forceinline__ float gelu_fast(float x){
  float t = 0.7978845608028654f * (x + 0.044715f * x * x * x);
  float e = __expf(2.0f * t);
  float th = 1.0f - 2.0f / (e + 1.0f);      // tanh(t), safe at +-inf
  return 0.5f * x * (1.0f + th);
}

// wf[n][ks]: B-fragment for outputs ob+n*16+(lane&15); frags n>=nv zeroed (N=224 tail)
__device__ __forceinline__ void load_wf(bf16x8 wf[4][7], const ushort_t* __restrict__ wm,
                                        int ob, int lane, int nv)
{
  bf16x8 zz = {0,0,0,0,0,0,0,0};
  #pragma unroll
  for (int n = 0; n < 4; ++n)
    #pragma unroll
    for (int ks = 0; ks < 7; ++ks)
      wf[n][ks] = (n < nv)
        ? *(const bf16x8*)&wm[(size_t)(ob + n*16 + (lane & 15)) * 224 + ks*32 + (lane >> 4)*8]
        : zz;
}

// shifted gather of 7 slots (each 8 channels) for conv2{1,2,3}
__device__ __forceinline__ void gather7(const ushort_t* __restrict__ h, int b, int vb,
                                        int cv, const int* sv, const int* su, bf16x8* gr)
{
  #pragma unroll
  for (int i = 0; i < 7; ++i){
    int v = sv[i], u = su[i];
    int g = u >> 2;
    int vg = vb + v;
    int d = vg >> 10, hh = (vg >> 5) & 31, w = vg & 31;
    int dd, hy, wx;
    if (cv == 0){ dd = d - (g - 3); hy = hh;               wx = w; }
    else if (cv == 1){ dd = d - 3;  hy = hh - (g - 3) - 3; wx = w - 3; }
    else { dd = d - 6;              hy = hh - 6;           wx = w - (g - 3) - 6; }
    bf16x8 val = {0,0,0,0,0,0,0,0};
    if ((unsigned)dd < 32u && (unsigned)hy < 32u && (unsigned)wx < 32u)
      val = *(const bf16x8*)&h[(((size_t)b << 15) + (size_t)((dd << 10) + (hy << 5) + wx)) * 224 + u*8];
    gr[i] = val;
  }
}

// ---------------------------------------------------------------------------
__global__ void k_wconv(const float* __restrict__ w1, const float* __restrict__ w2,
                        const float* __restrict__ w3, const float* __restrict__ w4,
                        const float* __restrict__ w5,
                        ushort_t* __restrict__ dst, float* __restrict__ stats)
{
  int i = blockIdx.x * 256 + threadIdx.x;
  if (blockIdx.x == 0 && threadIdx.x < 16) stats[threadIdx.x] = 0.f;
  if (i < 5 * DIM * DIM){
    int m = i / (DIM * DIM), r = i - m * (DIM * DIM);
    const float* s = (m == 0) ? w1 : (m == 1) ? w2 : (m == 2) ? w3 : (m == 3) ? w4 : w5;
    dst[i] = f2bf(s[r]);
  }
}

// ---------------------------------------------------------------------------
// K1: h0[b][v][c] = conv1(x) + b1 (bf16) + stats atomics.  N-slice 64/block.
// ---------------------------------------------------------------------------
__global__ __launch_bounds__(256, 2) void k_gemm1(
    const float* __restrict__ x, const ushort_t* __restrict__ w1,
    const float* __restrict__ b1, ushort_t* __restrict__ h0, float* __restrict__ stats)
{
  __shared__ __align__(16) ushort_t Abuf[2][64 * 232];
  __shared__ float red[8];
  int tid = threadIdx.x, lane = tid & 63, wid = tid >> 6;
  int task = ((blockIdx.x & 7) << 7) | (blockIdx.x >> 3);   // nwg=1024, q=128
  int nh = task & 3, tg = task >> 2;                         // tg in [0,256)
  int ob = nh << 6;
  int nv = (ob == 192) ? 2 : 4;                              // valid 16-col frags
  int tile0 = tg * 4;
  int b = tile0 >> 9;

  bf16x8 wf[4][7];
  load_wf(wf, w1, ob, lane, nv);
  float bias[4];
  #pragma unroll
  for (int n = 0; n < 4; ++n)
    bias[n] = (n < nv) ? b1[ob + n*16 + (lane & 15)] : 0.f;

  { // prologue: stage tile 0
    int vb = (tile0 & 511) << 6;
    const float* xp = x + ((size_t)b * 224) * 32768 + vb + (tid & 63);
    int v = tid & 63;
    #pragma unroll
    for (int i = 0; i < 7; ++i){
      int u = (tid >> 6) + i * 4;
      bf16x8 pv;
      #pragma unroll
      for (int j = 0; j < 8; ++j) pv[j] = (short)f2bf(xp[(size_t)(u*8 + j) * 32768]);
      *(bf16x8*)&Abuf[0][v * 232 + u * 8] = pv;
    }
  }
  __syncthreads();

  float lsum = 0.f, lsq = 0.f;
  f32x4 zz = {0.f,0.f,0.f,0.f};

  for (int t = 0; t < 4; ++t){
    int tile = tile0 + t;
    int vb = (tile & 511) << 6;
    float xr[7][8];
    if (t < 3){
      int vb2 = ((tile + 1) & 511) << 6;
      const float* xp = x + ((size_t)b * 224) * 32768 + vb2 + (tid & 63);
      #pragma unroll
      for (int i = 0; i < 7; ++i){
        int u = (tid >> 6) + i * 4;
        #pragma unroll
        for (int j = 0; j < 8; ++j) xr[i][j] = xp[(size_t)(u*8 + j) * 32768];
      }
    }
    f32x4 acc[4] = {zz, zz, zz, zz};
    const ushort_t* A = Abuf[t & 1];
    #pragma unroll
    for (int ks = 0; ks < 7; ++ks){
      bf16x8 af = *(const bf16x8*)&A[(wid*16 + (lane & 15)) * 232 + (ks*4 + (lane >> 4)) * 8];
      #pragma unroll
      for (int n = 0; n < 4; ++n)
        acc[n] = __builtin_amdgcn_mfma_f32_16x16x32_bf16(af, wf[n][ks], acc[n], 0, 0, 0);
    }
    __syncthreads();                       // all reads of Abuf[t&1] done
    if (t < 3){
      int v = tid & 63;
      #pragma unroll
      for (int i = 0; i < 7; ++i){
        int u = (tid >> 6) + i * 4;
        bf16x8 pv;
        #pragma unroll
        for (int j = 0; j < 8; ++j) pv[j] = (short)f2bf(xr[i][j]);
        *(bf16x8*)&Abuf[(t + 1) & 1][v * 232 + u * 8] = pv;
      }
    }
    ushort_t* Ebf = (ushort_t*)Abuf[t & 1];  // [64][72] bf16
    #pragma unroll
    for (int n = 0; n < 4; ++n)
      #pragma unroll
      for (int r = 0; r < 4; ++r){
        float val = acc[n][r] + bias[n];
        lsum += val; lsq += val * val;
        Ebf[(wid*16 + (lane >> 4)*4 + r) * 72 + n*16 + (lane & 15)] = f2bf(val);
      }
    __syncthreads();
    size_t base = (((size_t)b << 15) + vb) * 224 + ob;
    #pragma unroll
    for (int i = 0; i < 2; ++i){
      int slot = tid + i * 256;
      int v = slot >> 3, u = slot & 7;
      if (ob + u*8 < 224)
        *(bf16x8*)&h0[base + (size_t)v * 224 + u * 8] = *(const bf16x8*)&Ebf[v * 72 + u * 8];
    }
  }
  #pragma unroll
  for (int off = 32; off; off >>= 1){
    lsum += __shfl_down(lsum, off);
    lsq  += __shfl_down(lsq,  off);
  }
  if (lane == 0){ red[wid*2] = lsum; red[wid*2 + 1] = lsq; }
  __syncthreads();
  if (tid == 0){
    atomicAdd(&stats[0 + b], red[0] + red[2] + red[4] + red[6]);
    atomicAdd(&stats[2 + b], red[1] + red[3] + red[5] + red[7]);
  }
}

// ---------------------------------------------------------------------------
__global__ void k_stats(const float* __restrict__ stats, int soff,
                        const float* __restrict__ g, const float* __restrict__ be,
                        float* __restrict__ Aout, float* __restrict__ Bout)
{
  int tid = threadIdx.x;
  const float invN = 1.0f / (float)((size_t)DIM * NVOX);
  for (int i = tid; i < 2 * DIM; i += 256){
    int b = i / DIM, c = i - b * DIM;
    float mu   = stats[soff + b] * invN;
    float var  = stats[soff + 2 + b] * invN - mu * mu;
    float rstd = rsqrtf(var + 1e-5f);
    float a = rstd * g[c];
    Aout[i] = a;
    Bout[i] = be[c] - mu * a;
  }
}

// ---------------------------------------------------------------------------
__global__ void k_act(ushort_t* __restrict__ h,
                      const float* __restrict__ A1, const float* __restrict__ B1)
{
  const size_t total = (size_t)2 * NVOX * 28;
  for (size_t idx = (size_t)blockIdx.x * 256 + threadIdx.x; idx < total;
       idx += (size_t)2048 * 256){
    int u = (int)(idx % 28);
    size_t bv = idx / 28;
    int b = (int)(bv >> 15);
    ushort_t* p = h + bv * 224 + u * 8;
    bf16x8 hv = *(const bf16x8*)p;
    const float* Ap = A1 + b * 224 + u * 8;
    const float* Bp = B1 + b * 224 + u * 8;
    #pragma unroll
    for (int i = 0; i < 8; ++i){
      float f = bf2f((unsigned short)hv[i]) * Ap[i] + Bp[i];
      hv[i] = (short)f2bf(gelu_fast(f));
    }
    *(bf16x8*)p = hv;
  }
}

// ---------------------------------------------------------------------------
// K4: s = sum_cv gelu(conv2x(shift_cv(h))), bf16 out + stats2 atomics
// ---------------------------------------------------------------------------
__global__ __launch_bounds__(256, 2) void k_shift(
    const ushort_t* __restrict__ h, const ushort_t* __restrict__ wall,
    const float* __restrict__ b21, const float* __restrict__ b22,
    const float* __restrict__ b23,
    ushort_t* __restrict__ sout, float* __restrict__ stats)
{
  __shared__ __align__(16) ushort_t Abuf[2][64 * 232];
  __shared__ float red[8];
  int tid = threadIdx.x, lane = tid & 63, wid = tid >> 6;
  int task = ((blockIdx.x & 7) << 8) | (blockIdx.x >> 3);  // nwg=2048, q=256
  int nh = task & 3, tg = task >> 2;                        // tg in [0,512)
  int ob = nh << 6;
  int nv = (ob == 192) ? 2 : 4;
  int tile0 = tg * 2;
  int b = tile0 >> 9;
  int sv[7], su[7];
  #pragma unroll
  for (int i = 0; i < 7; ++i){ int s = tid + i*256; sv[i] = (s * 9363) >> 18; su[i] = s - sv[i] * 28; }

  float biasv[3][4];
  #pragma unroll
  for (int n = 0; n < 4; ++n){
    int o = ob + n*16 + (lane & 15);
    biasv[0][n] = (n < nv) ? b21[o] : 0.f;
    biasv[1][n] = (n < nv) ? b22[o] : 0.f;
    biasv[2][n] = (n < nv) ? b23[o] : 0.f;
  }

  bf16x8 wf[4][7];
  load_wf(wf, wall + (size_t)1 * 224 * 224, ob, lane, nv);  // conv21
  bf16x8 gr[7];
  gather7(h, b, (tile0 & 511) << 6, 0, sv, su, gr);
  #pragma unroll
  for (int i = 0; i < 7; ++i) *(bf16x8*)&Abuf[0][sv[i]*232 + su[i]*8] = gr[i];
  __syncthreads();

  f32x4 zz = {0.f,0.f,0.f,0.f};
  f32x4 sacc[2][4] = {{zz,zz,zz,zz},{zz,zz,zz,zz}};

  #pragma unroll
  for (int s = 0; s < 6; ++s){
    const int cv = s >> 1, tl = s & 1;
    if (s < 5)
      gather7(h, b, ((tile0 + ((s + 1) & 1)) & 511) << 6, (s + 1) >> 1, sv, su, gr);
    f32x4 acc[4] = {zz, zz, zz, zz};
    const ushort_t* A = Abuf[tl];
    #pragma unroll
    for (int ks = 0; ks < 7; ++ks){
      bf16x8 af = *(const bf16x8*)&A[(wid*16 + (lane & 15)) * 232 + (ks*4 + (lane >> 4)) * 8];
      #pragma unroll
      for (int n = 0; n < 4; ++n)
        acc[n] = __builtin_amdgcn_mfma_f32_16x16x32_bf16(af, wf[n][ks], acc[n], 0, 0, 0);
    }
    #pragma unroll
    for (int n = 0; n < 4; ++n)
      #pragma unroll
      for (int r = 0; r < 4; ++r)
        sacc[tl][n][r] += gelu_fast(acc[n][r] + biasv[cv][n]);
    if (tl == 1 && cv < 2)
      load_wf(wf, wall + (size_t)(2 + cv) * 224 * 224, ob, lane, nv);
    if (s < 5){
      #pragma unroll
      for (int i = 0; i < 7; ++i) *(bf16x8*)&Abuf[(s + 1) & 1][sv[i]*232 + su[i]*8] = gr[i];
    }
    __syncthreads();
  }

  float lsum = 0.f, lsq = 0.f;
  #pragma unroll
  for (int tl = 0; tl < 2; ++tl){
    ushort_t* Ebf = (ushort_t*)Abuf[tl];
    #pragma unroll
    for (int n = 0; n < 4; ++n)
      #pragma unroll
      for (int r = 0; r < 4; ++r){
        float val = sacc[tl][n][r];
        lsum += val; lsq += val * val;
        Ebf[(wid*16 + (lane >> 4)*4 + r) * 72 + n*16 + (lane & 15)] = f2bf(val);
      }
  }
  __syncthreads();
  #pragma unroll
  for (int tl = 0; tl < 2; ++tl){
    const ushort_t* Ebf = (const ushort_t*)Abuf[tl];
    size_t base = (((size_t)b << 15) + (((tile0 + tl) & 511) << 6)) * 224 + ob;
    #pragma unroll
    for (int i = 0; i < 2; ++i){
      int slot = tid + i * 256;
      int v = slot >> 3, u = slot & 7;
      if (ob + u*8 < 224)
        *(bf16x8*)&sout[base + (size_t)v * 224 + u * 8] = *(const bf16x8*)&Ebf[v * 72 + u * 8];
    }
  }
  #pragma unroll
  for (int off = 32; off; off >>= 1){
    lsum += __shfl_down(lsum, off);
    lsq  += __shfl_down(lsq,  off);
  }
  if (lane == 0){ red[wid*2] = lsum; red[wid*2 + 1] = lsq; }
  __syncthreads();
  if (tid == 0){
    atomicAdd(&stats[4 + b], red[0] + red[2] + red[4] + red[6]);
    atomicAdd(&stats[6 + b], red[1] + red[3] + red[5] + red[7]);
  }
}

// ---------------------------------------------------------------------------
// K6: y = conv3(gn2(s)) + b3 + x.  GN2 affine folded into wf and bias.
// ---------------------------------------------------------------------------
__global__ __launch_bounds__(256, 2) void k_out(
    const ushort_t* __restrict__ sbf, const ushort_t* __restrict__ w3,
    const float* __restrict__ b3,
    const float* __restrict__ A2, const float* __restrict__ B2,
    const float* __restrict__ xorig, float* __restrict__ y)
{
  __shared__ __align__(16) ushort_t Abuf[2][64 * 232];
  int tid = threadIdx.x, lane = tid & 63, wid = tid >> 6;
  int task = ((blockIdx.x & 7) << 7) | (blockIdx.x >> 3);   // nwg=1024, q=128
  int nh = task & 3, tg = task >> 2;
  int ob = nh << 6;
  int nv = (ob == 192) ? 2 : 4;
  int tile0 = tg * 4;
  int b = tile0 >> 9;
  int sv[7], su[7];
  #pragma unroll
  for (int i = 0; i < 7; ++i){ int s = tid + i*256; sv[i] = (s * 9363) >> 18; su[i] = s - sv[i] * 28; }

  bf16x8 wf[4][7];
  load_wf(wf, w3, ob, lane, nv);
  // fold GN2 affine: wf *= A2[k]; bias = b3 + sum_k W3[o][k]*B2[k]
  float bsum[4] = {0.f, 0.f, 0.f, 0.f};
  {
    const float* A2p = A2 + b * 224;
    const float* B2p = B2 + b * 224;
    #pragma unroll
    for (int ks = 0; ks < 7; ++ks){
      int k0 = ks*32 + (lane >> 4)*8;
      float av[8], bv[8];
      #pragma unroll
      for (int j = 0; j < 8; ++j){ av[j] = A2p[k0 + j]; bv[j] = B2p[k0 + j]; }
      #pragma unroll
      for (int n = 0; n < 4; ++n){
        if (n < nv){
          bf16x8 wv = wf[n][ks];
          #pragma unroll
          for (int j = 0; j < 8; ++j){
            float f = bf2f((unsigned short)wv[j]);
            bsum[n] += f * bv[j];
            wv[j] = (short)f2bf(f * av[j]);
          }
          wf[n][ks] = wv;
        }
      }
    }
  }
  float bias[4];
  #pragma unroll
  for (int n = 0; n < 4; ++n){
    float s0 = bsum[n];
    s0 += __shfl_xor(s0, 16);
    s0 += __shfl_xor(s0, 32);
    bias[n] = (n < nv) ? b3[ob + n*16 + (lane & 15)] + s0 : 0.f;
  }

  { // prologue: stage tile 0 (plain copy)
    int vb = (tile0 & 511) << 6;
    #pragma unroll
    for (int i = 0; i < 7; ++i){
      bf16x8 val = *(const bf16x8*)&sbf[(((size_t)b << 15) + vb + sv[i]) * 224 + su[i]*8];
      *(bf16x8*)&Abuf[0][sv[i]*232 + su[i]*8] = val;
    }
  }
  __syncthreads();

  f32x4 zz = {0.f,0.f,0.f,0.f};
  bf16x8 gr[7];
  for (int t = 0; t < 4; ++t){
    int tile = tile0 + t;
    int vb = (tile & 511) << 6;
    if (t < 3){
      int vb2 = ((tile + 1) & 511) << 6;
      #pragma unroll
      for (int i = 0; i < 7; ++i)
        gr[i] = *(const bf16x8*)&sbf[(((size_t)b << 15) + vb2 + sv[i]) * 224 + su[i]*8];
    }
    f32x4 acc[4] = {zz, zz, zz, zz};
    const ushort_t* A = Abuf[t & 1];
    #pragma unroll
    for (int ks = 0; ks < 7; ++ks){
      bf16x8 af = *(const bf16x8*)&A[(wid*16 + (lane & 15)) * 232 + (ks*4 + (lane >> 4)) * 8];
      #pragma unroll
      for (int n = 0; n < 4; ++n)
        acc[n] = __builtin_amdgcn_mfma_f32_16x16x32_bf16(af, wf[n][ks], acc[n], 0, 0, 0);
    }
    __syncthreads();
    if (t < 3){
      #pragma unroll
      for (int i = 0; i < 7; ++i)
        *(bf16x8*)&Abuf[(t + 1) & 1][sv[i]*232 + su[i]*8] = gr[i];
    }
    float* Et = (float*)Abuf[t & 1];        // [64][66] f32
    #pragma unroll
    for (int n = 0; n < 4; ++n)
      #pragma unroll
      for (int r = 0; r < 4; ++r)
        Et[(n*16 + (lane & 15)) * 66 + wid*16 + (lane >> 4)*4 + r] = acc[n][r] + bias[n];
    __syncthreads();
    int v = tid & 63;
    size_t gbase = (((size_t)b * 224 + ob) << 15) + vb + v;
    #pragma unroll
    for (int i = 0; i < 16; ++i){
      int row = (tid >> 6) + i * 4;
      if (ob + row < 224){
        size_t gi = gbase + ((size_t)row << 15);
        y[gi] = Et[row * 66 + v] + xorig[gi];
      }
    }
  }
}

// ---------------------------------------------------------------------------
extern "C" void kernel_launch(void* const* d_in, const int* in_sizes, int n_in,
                              void* d_out, int out_size, void* d_ws, size_t ws_size,
                              hipStream_t stream)
{
  const float* x    = (const float*)d_in[0];
  const float* w1f  = (const float*)d_in[1];
  const float* b1   = (const float*)d_in[2];
  const float* w21f = (const float*)d_in[3];
  const float* b21  = (const float*)d_in[4];
  const float* w22f = (const float*)d_in[5];
  const float* b22  = (const float*)d_in[6];
  const float* w23f = (const float*)d_in[7];
  const float* b23  = (const float*)d_in[8];
  const float* w3f  = (const float*)d_in[9];
  const float* b3   = (const float*)d_in[10];
  const float* n1g  = (const float*)d_in[11];
  const float* n1b  = (const float*)d_in[12];
  const float* n2g  = (const float*)d_in[13];
  const float* n2b  = (const float*)d_in[14];
  float* y = (float*)d_out;

  float* stats = (float*)d_ws;                                   // 16 floats
  float* A1 = stats + 16; float* B1 = A1 + 448;
  float* A2 = B1 + 448;   float* B2 = A2 + 448;
  ushort_t* Wbf = (ushort_t*)((char*)d_ws + 8192);               // 5*224*224 bf16
  ushort_t* sbf = (ushort_t*)((char*)d_ws + 524288);             // 2*32768*224 bf16
  ushort_t* hbf = (ushort_t*)d_out;                              // h0/h (dead before k_out writes y)

  k_wconv<<<980, 256, 0, stream>>>(w1f, w21f, w22f, w23f, w3f, Wbf, stats);
  k_gemm1<<<1024, 256, 0, stream>>>(x, Wbf, b1, hbf, stats);
  k_stats<<<1, 256, 0, stream>>>(stats, 0, n1g, n1b, A1, B1);
  k_act<<<2048, 256, 0, stream>>>(hbf, A1, B1);
  k_shift<<<2048, 256, 0, stream>>>(hbf, Wbf, b21, b22, b23, sbf, stats);
  k_stats<<<1, 256, 0, stream>>>(stats, 4, n2g, n2b, A2, B2);
  k_out<<<1024, 256, 0, stream>>>(sbf, Wbf + 4 * DIM * DIM, b3, A2, B2, x, y);
}